// Round 1
// baseline (1642.579 us; speedup 1.0000x reference)
//
#include <hip/hip_runtime.h>
#include <hip/hip_bf16.h>

// Mamba backbone, fp32 baseline.
// Shapes: B=4, N=2048, D_MODEL=512, D_INNER=1024, D_STATE=16, D_CONV=4, DT_RANK=32, L=3.

#define DMODEL 512
#define DINNER 1024
#define DSTATE 16
#define DTRANK 32
#define BSZ 4
#define SEQ 2048
#define NTOK (BSZ * SEQ) /* 8192 */
#define NCH 64           /* scan chunks per sequence */
#define CHUNK 32         /* SEQ / NCH */
#define LN_EPS 1e-5f

__device__ __forceinline__ float fast_exp(float x) { return __expf(x); }
__device__ __forceinline__ float siluf_(float x) { return x / (1.f + __expf(-x)); }
__device__ __forceinline__ float softplusf_(float x) {
    // log1p(exp(x)), stable form: max(x,0) + log1p(exp(-|x|))
    return fmaxf(x, 0.f) + log1pf(__expf(-fabsf(x)));
}

// ---------------- mask * x ----------------
__global__ __launch_bounds__(256) void mask_kernel(const float* __restrict__ x,
                                                   const int* __restrict__ mask,
                                                   float* __restrict__ out) {
    int idx = blockIdx.x * 256 + threadIdx.x;
    int row = idx >> 9; // / DMODEL
    out[idx] = mask[row] ? x[idx] : 0.f;
}

// ---------------- GEMM  C[M,N] = A[M,K] * B[N,K]^T  (both row-major, K contig) ----
// BM=BN=64, BK=16, 256 threads, 4x4 microtile.
// EPI: 0 = none, 1 = softplus(acc + bias[col])
template <int EPI>
__global__ __launch_bounds__(256) void gemm_abt(const float* __restrict__ A, int lda,
                                                const float* __restrict__ B, int ldb,
                                                float* __restrict__ C,
                                                const float* __restrict__ bias,
                                                int M, int N, int K) {
    __shared__ float As[16][68]; // [k][m], pad to 68 for bank spread + f4 align
    __shared__ float Bs[16][68]; // [k][n]
    const int tid = threadIdx.x;
    const int row0 = blockIdx.y * 64;
    const int col0 = blockIdx.x * 64;
    const int trow = tid >> 4;   // 0..15
    const int tcol = tid & 15;   // 0..15
    const int lr = tid >> 2;     // 0..63 (tile row for staging)
    const int lk = (tid & 3) * 4;

    float acc[4][4] = {};
    for (int k0 = 0; k0 < K; k0 += 16) {
        float4 av = *(const float4*)&A[(size_t)(row0 + lr) * lda + k0 + lk];
        float4 bv = *(const float4*)&B[(size_t)(col0 + lr) * ldb + k0 + lk];
        __syncthreads(); // previous iteration's reads done
        As[lk + 0][lr] = av.x; As[lk + 1][lr] = av.y;
        As[lk + 2][lr] = av.z; As[lk + 3][lr] = av.w;
        Bs[lk + 0][lr] = bv.x; Bs[lk + 1][lr] = bv.y;
        Bs[lk + 2][lr] = bv.z; Bs[lk + 3][lr] = bv.w;
        __syncthreads();
#pragma unroll
        for (int k = 0; k < 16; k++) {
            float4 a4 = *(const float4*)&As[k][trow << 2];
            float4 b4 = *(const float4*)&Bs[k][tcol << 2];
            float am[4] = {a4.x, a4.y, a4.z, a4.w};
            float bn[4] = {b4.x, b4.y, b4.z, b4.w};
#pragma unroll
            for (int i = 0; i < 4; i++)
#pragma unroll
                for (int j = 0; j < 4; j++)
                    acc[i][j] = fmaf(am[i], bn[j], acc[i][j]);
        }
    }
#pragma unroll
    for (int i = 0; i < 4; i++) {
        int r = row0 + (trow << 2) + i;
        int cbase = col0 + (tcol << 2);
        float4 o;
        if (EPI == 1) {
            o.x = softplusf_(acc[i][0] + bias[cbase + 0]);
            o.y = softplusf_(acc[i][1] + bias[cbase + 1]);
            o.z = softplusf_(acc[i][2] + bias[cbase + 2]);
            o.w = softplusf_(acc[i][3] + bias[cbase + 3]);
        } else {
            o.x = acc[i][0]; o.y = acc[i][1]; o.z = acc[i][2]; o.w = acc[i][3];
        }
        *(float4*)&C[(size_t)r * N + cbase] = o;
    }
}

// ---------------- depthwise causal conv (D_CONV=4) + SiLU ----------------
// in: xz rows of length 2048 (first DINNER cols are xc), out: xc[NTOK][DINNER]
__global__ __launch_bounds__(256) void conv_silu_kernel(const float* __restrict__ xz,
                                                        const float* __restrict__ cw,
                                                        const float* __restrict__ cb,
                                                        float* __restrict__ xc) {
    int idx = blockIdx.x * 256 + threadIdx.x; // NTOK*DINNER
    int c = idx & (DINNER - 1);
    int t = idx >> 10;
    int n = t & (SEQ - 1);
    const float* base = xz + (size_t)t * (2 * DINNER) + c;
    const float* w = cw + c * 4;
    float acc = cb[c];
    if (n >= 3) acc = fmaf(w[0], base[-3 * 2 * DINNER], acc);
    if (n >= 2) acc = fmaf(w[1], base[-2 * 2 * DINNER], acc);
    if (n >= 1) acc = fmaf(w[2], base[-1 * 2 * DINNER], acc);
    acc = fmaf(w[3], base[0], acc);
    xc[idx] = siluf_(acc);
}

// ---------------- selective scan, chunked ----------------
// pass 1: per (b, d, chunk) compute local h (from 0) and decay product P
__global__ __launch_bounds__(256) void scan1_kernel(const float* __restrict__ delta,
                                                    const float* __restrict__ xc,
                                                    const float* __restrict__ dbc,
                                                    const float* __restrict__ A_log,
                                                    float* __restrict__ P,
                                                    float* __restrict__ HL) {
    int blk = blockIdx.x;           // b*256 + c*4 + dg
    int dg = blk & 3;
    int c = (blk >> 2) & (NCH - 1);
    int b = blk >> 8;
    int d = dg * 256 + threadIdx.x;

    float a[DSTATE], h[DSTATE], p[DSTATE];
#pragma unroll
    for (int s = 0; s < DSTATE; s++) {
        a[s] = -fast_exp(A_log[d * DSTATE + s]);
        h[s] = 0.f;
        p[s] = 1.f;
    }
    int rowbase = b * SEQ + c * CHUNK;
    for (int i = 0; i < CHUNK; i++) {
        size_t row = rowbase + i;
        float dlt = delta[row * DINNER + d];
        float u = xc[row * DINNER + d];
        float du = dlt * u;
        const float* bs = dbc + row * 64 + DTRANK;
#pragma unroll
        for (int s = 0; s < DSTATE; s++) {
            float ex = fast_exp(dlt * a[s]);
            h[s] = fmaf(ex, h[s], du * bs[s]);
            p[s] *= ex;
        }
    }
    size_t o = ((size_t)(b * NCH + c) * DINNER + d) * DSTATE;
#pragma unroll
    for (int s = 0; s < DSTATE; s += 4) {
        *(float4*)&P[o + s] = make_float4(p[s], p[s + 1], p[s + 2], p[s + 3]);
        *(float4*)&HL[o + s] = make_float4(h[s], h[s + 1], h[s + 2], h[s + 3]);
    }
}

// pass 2: stitch chunk boundaries; HL becomes Hinit (state at chunk start)
__global__ __launch_bounds__(256) void scan2_kernel(const float* __restrict__ P,
                                                    float* __restrict__ HL) {
    int idx = blockIdx.x * 256 + threadIdx.x; // BSZ*DINNER*DSTATE = 65536
    int b = idx >> 14;
    int ds = idx & 16383;
    float H = 0.f;
    for (int c = 0; c < NCH; c++) {
        size_t o = ((size_t)(b * NCH + c) << 14) + ds;
        float pv = P[o];
        float hl = HL[o];
        HL[o] = H; // initial state for chunk c
        H = fmaf(pv, H, hl);
    }
}

// pass 3: rescan with correct init, fused epilogue; y overwrites delta in place
__global__ __launch_bounds__(256) void scan3_kernel(float* __restrict__ delta_y,
                                                    const float* __restrict__ xc,
                                                    const float* __restrict__ xz,
                                                    const float* __restrict__ dbc,
                                                    const float* __restrict__ A_log,
                                                    const float* __restrict__ Dp,
                                                    const float* __restrict__ HL) {
    int blk = blockIdx.x;
    int dg = blk & 3;
    int c = (blk >> 2) & (NCH - 1);
    int b = blk >> 8;
    int d = dg * 256 + threadIdx.x;

    float a[DSTATE], h[DSTATE];
    size_t o = ((size_t)(b * NCH + c) * DINNER + d) * DSTATE;
#pragma unroll
    for (int s = 0; s < DSTATE; s++) {
        a[s] = -fast_exp(A_log[d * DSTATE + s]);
        h[s] = HL[o + s];
    }
    float dd = Dp[d];
    int rowbase = b * SEQ + c * CHUNK;
    for (int i = 0; i < CHUNK; i++) {
        size_t row = rowbase + i;
        float dlt = delta_y[row * DINNER + d];
        float u = xc[row * DINNER + d];
        float z = xz[row * (2 * DINNER) + DINNER + d];
        float du = dlt * u;
        const float* bs = dbc + row * 64 + DTRANK;
        const float* cs = dbc + row * 64 + DTRANK + DSTATE;
        float y = 0.f;
#pragma unroll
        for (int s = 0; s < DSTATE; s++) {
            float ex = fast_exp(dlt * a[s]);
            h[s] = fmaf(ex, h[s], du * bs[s]);
            y = fmaf(h[s], cs[s], y);
        }
        y = fmaf(dd, u, y);
        y *= siluf_(z);
        delta_y[row * DINNER + d] = y;
    }
}

// ---------------- LayerNorm + mask ----------------
__global__ __launch_bounds__(256) void ln_kernel(const float* __restrict__ X,
                                                 const int* __restrict__ mask,
                                                 const float* __restrict__ nw,
                                                 const float* __restrict__ nb,
                                                 float* __restrict__ out) {
    int wave = threadIdx.x >> 6;
    int lane = threadIdx.x & 63;
    int row = blockIdx.x * 4 + wave;
    const float* xr = X + (size_t)row * DMODEL;
    int cb = lane * 8;
    float4 v0 = *(const float4*)&xr[cb];
    float4 v1 = *(const float4*)&xr[cb + 4];
    float sum = v0.x + v0.y + v0.z + v0.w + v1.x + v1.y + v1.z + v1.w;
#pragma unroll
    for (int off = 32; off >= 1; off >>= 1) sum += __shfl_xor(sum, off, 64);
    float mu = sum * (1.f / DMODEL);
    float d0 = v0.x - mu, d1 = v0.y - mu, d2 = v0.z - mu, d3 = v0.w - mu;
    float d4 = v1.x - mu, d5 = v1.y - mu, d6 = v1.z - mu, d7 = v1.w - mu;
    float vs = d0 * d0 + d1 * d1 + d2 * d2 + d3 * d3 + d4 * d4 + d5 * d5 + d6 * d6 + d7 * d7;
#pragma unroll
    for (int off = 32; off >= 1; off >>= 1) vs += __shfl_xor(vs, off, 64);
    float sc = rsqrtf(vs * (1.f / DMODEL) + LN_EPS);
    float mk = mask[row] ? 1.f : 0.f;
    float4 w0 = *(const float4*)&nw[cb];
    float4 w1 = *(const float4*)&nw[cb + 4];
    float4 b0 = *(const float4*)&nb[cb];
    float4 b1 = *(const float4*)&nb[cb + 4];
    float4 o0, o1;
    o0.x = (d0 * sc * w0.x + b0.x) * mk;
    o0.y = (d1 * sc * w0.y + b0.y) * mk;
    o0.z = (d2 * sc * w0.z + b0.z) * mk;
    o0.w = (d3 * sc * w0.w + b0.w) * mk;
    o1.x = (d4 * sc * w1.x + b1.x) * mk;
    o1.y = (d5 * sc * w1.y + b1.y) * mk;
    o1.z = (d6 * sc * w1.z + b1.z) * mk;
    o1.w = (d7 * sc * w1.w + b1.w) * mk;
    float* orow = out + (size_t)row * DMODEL + cb;
    *(float4*)&orow[0] = o0;
    *(float4*)&orow[4] = o1;
}

extern "C" void kernel_launch(void* const* d_in, const int* in_sizes, int n_in,
                              void* d_out, int out_size, void* d_ws, size_t ws_size,
                              hipStream_t stream) {
    const float* x = (const float*)d_in[0];
    const int* mask = (const int*)d_in[1];
    const float* ipw = (const float*)d_in[2];
    const float* cw = (const float*)d_in[3];
    const float* cb = (const float*)d_in[4];
    const float* xpw = (const float*)d_in[5];
    const float* dtw = (const float*)d_in[6];
    const float* dtb = (const float*)d_in[7];
    const float* Alog = (const float*)d_in[8];
    const float* Dp = (const float*)d_in[9];
    const float* opw = (const float*)d_in[10];
    const float* nw = (const float*)d_in[11];
    const float* nb = (const float*)d_in[12];

    float* ws = (float*)d_ws;
    float* Xa = ws;
    float* Xb = Xa + (size_t)NTOK * DMODEL;
    float* xz = Xb + (size_t)NTOK * DMODEL;        // NTOK x 2048
    float* xc = xz + (size_t)NTOK * 2 * DINNER;    // NTOK x 1024
    float* dbc = xc + (size_t)NTOK * DINNER;       // NTOK x 64
    float* delta = dbc + (size_t)NTOK * 64;        // NTOK x 1024 (becomes y)
    float* P = delta + (size_t)NTOK * DINNER;      // B*NCH*DINNER*DSTATE
    float* HL = P + (size_t)BSZ * NCH * DINNER * DSTATE;

    mask_kernel<<<NTOK * DMODEL / 256, 256, 0, stream>>>(x, mask, Xa);

    float* cur = Xa;
    float* nxt = Xb;
    for (int l = 0; l < 3; l++) {
        const float* ipw_l = ipw + (size_t)l * 2 * DINNER * DMODEL;
        const float* cw_l = cw + (size_t)l * DINNER * 4;
        const float* cb_l = cb + (size_t)l * DINNER;
        const float* xpw_l = xpw + (size_t)l * 64 * DINNER;
        const float* dtw_l = dtw + (size_t)l * DINNER * DTRANK;
        const float* dtb_l = dtb + (size_t)l * DINNER;
        const float* Alog_l = Alog + (size_t)l * DINNER * DSTATE;
        const float* Dp_l = Dp + (size_t)l * DINNER;
        const float* opw_l = opw + (size_t)l * DMODEL * DINNER;

        dim3 g1(2 * DINNER / 64, NTOK / 64);
        gemm_abt<0><<<g1, 256, 0, stream>>>(cur, DMODEL, ipw_l, DMODEL, xz, nullptr,
                                            NTOK, 2 * DINNER, DMODEL);
        conv_silu_kernel<<<NTOK * DINNER / 256, 256, 0, stream>>>(xz, cw_l, cb_l, xc);
        dim3 g2(1, NTOK / 64);
        gemm_abt<0><<<g2, 256, 0, stream>>>(xc, DINNER, xpw_l, DINNER, dbc, nullptr,
                                            NTOK, 64, DINNER);
        dim3 g3(DINNER / 64, NTOK / 64);
        gemm_abt<1><<<g3, 256, 0, stream>>>(dbc, 64, dtw_l, DTRANK, delta, dtb_l,
                                            NTOK, DINNER, DTRANK);
        scan1_kernel<<<BSZ * NCH * 4, 256, 0, stream>>>(delta, xc, dbc, Alog_l, P, HL);
        scan2_kernel<<<BSZ * DINNER * DSTATE / 256, 256, 0, stream>>>(P, HL);
        scan3_kernel<<<BSZ * NCH * 4, 256, 0, stream>>>(delta, xc, xz, dbc, Alog_l, Dp_l, HL);
        dim3 g4(DMODEL / 64, NTOK / 64);
        gemm_abt<0><<<g4, 256, 0, stream>>>(delta, DINNER, opw_l, DINNER, nxt, nullptr,
                                            NTOK, DMODEL, DINNER);
        float* t = cur; cur = nxt; nxt = t;
    }
    ln_kernel<<<NTOK / 4, 256, 0, stream>>>(cur, mask, nw, nb, (float*)d_out);
}

// Round 2
// 1071.240 us; speedup vs baseline: 1.5333x; 1.5333x over previous
//
#include <hip/hip_runtime.h>
#include <hip/hip_bf16.h>

// Mamba backbone. Split-bf16 MFMA GEMMs for in_proj/out_proj, fp32 elsewhere.
// B=4, N=2048, D_MODEL=512, D_INNER=1024, D_STATE=16, D_CONV=4, DT_RANK=32, L=3.

#define DMODEL 512
#define DINNER 1024
#define DSTATE 16
#define DTRANK 32
#define BSZ 4
#define SEQ 2048
#define NTOK (BSZ * SEQ) /* 8192 */
#define NCH 32           /* scan chunks per sequence */
#define CHUNK 64         /* SEQ / NCH */
#define LN_EPS 1e-5f

typedef __attribute__((ext_vector_type(8))) short bf16x8;
typedef __attribute__((ext_vector_type(4))) float f32x4;

__device__ __forceinline__ float siluf_(float x) { return x / (1.f + __expf(-x)); }
__device__ __forceinline__ float softplusf_(float x) {
    return fmaxf(x, 0.f) + log1pf(__expf(-fabsf(x)));
}
__device__ __forceinline__ ushort f2bf(float f) {
    unsigned u = __float_as_uint(f);
    u += 0x7fffu + ((u >> 16) & 1u);
    return (ushort)(u >> 16);
}
__device__ __forceinline__ float bf2f(ushort h) {
    return __uint_as_float((unsigned)h << 16);
}

// ---------------- fp32 -> (hi,lo) bf16 split, 4 elems/thread ----------------
__global__ __launch_bounds__(256) void split_kernel(const float* __restrict__ x,
                                                    ushort* __restrict__ hi,
                                                    ushort* __restrict__ lo) {
    int i = blockIdx.x * 256 + threadIdx.x;
    float4 v = ((const float4*)x)[i];
    ushort4 h, l;
    h.x = f2bf(v.x); l.x = f2bf(v.x - bf2f(h.x));
    h.y = f2bf(v.y); l.y = f2bf(v.y - bf2f(h.y));
    h.z = f2bf(v.z); l.z = f2bf(v.z - bf2f(h.z));
    h.w = f2bf(v.w); l.w = f2bf(v.w - bf2f(h.w));
    ((ushort4*)hi)[i] = h;
    ((ushort4*)lo)[i] = l;
}

// ---------------- mask * x, fused split ----------------
__global__ __launch_bounds__(256) void mask_split_kernel(const float* __restrict__ x,
                                                         const int* __restrict__ mask,
                                                         ushort* __restrict__ hi,
                                                         ushort* __restrict__ lo) {
    int i = blockIdx.x * 256 + threadIdx.x; // 4-elem groups; 128 groups per row
    int row = i >> 7;
    float4 v = ((const float4*)x)[i];
    if (!mask[row]) { v.x = 0.f; v.y = 0.f; v.z = 0.f; v.w = 0.f; }
    ushort4 h, l;
    h.x = f2bf(v.x); l.x = f2bf(v.x - bf2f(h.x));
    h.y = f2bf(v.y); l.y = f2bf(v.y - bf2f(h.y));
    h.z = f2bf(v.z); l.z = f2bf(v.z - bf2f(h.z));
    h.w = f2bf(v.w); l.w = f2bf(v.w - bf2f(h.w));
    ((ushort4*)hi)[i] = h;
    ((ushort4*)lo)[i] = l;
}

// ---------------- split-bf16 MFMA GEMM ----------------
// C[M,N] = A[M,KK] * B[N,KK]^T with A = Ahi+Alo, B = Bhi+Blo (bf16 pairs).
// 3 segments: Ahi*Bhi + Ahi*Blo + Alo*Bhi. BM=128, BK=32, 4 waves.
// BN=128: wave grid 2x2 (64x64 each). BN=64: wave grid 2x2 (64x32 each).
// SPLITOUT: write C as bf16 (hi,lo) pair instead of fp32.
template <int BN, int KK, bool SPLITOUT>
__global__ __launch_bounds__(256) void gemm_split(
    const ushort* __restrict__ Ahi, const ushort* __restrict__ Alo,
    const ushort* __restrict__ Bhi, const ushort* __restrict__ Blo,
    float* __restrict__ C, ushort* __restrict__ Chi, ushort* __restrict__ Clo,
    int N) {
    constexpr int BM = 128, BK = 32;
    constexpr int NCHUNK = 8 + BN / 16; // 1KB staging chunks (A:8, B:BN/16)
    constexpr int NFB = BN / 32;        // B-fragments per wave
    __shared__ ushort As[BM * BK];      // 8KB, row-major [128][32]
    __shared__ ushort Bs[BN * BK];
    const int tid = threadIdx.x;
    const int w = tid >> 6, l = tid & 63;
    const int row0 = blockIdx.y * BM;
    const int col0 = blockIdx.x * BN;
    const int wm = (w >> 1) * 64;
    const int wn = (w & 1) * (BN / 2);
    const int lrow = l >> 2;      // row within 16-row chunk
    const int lcol = (l & 3) * 8; // k offset

    f32x4 acc[4][NFB];
#pragma unroll
    for (int i = 0; i < 4; i++)
#pragma unroll
        for (int j = 0; j < NFB; j++)
#pragma unroll
            for (int r = 0; r < 4; r++) acc[i][j][r] = 0.f;

#pragma unroll 1
    for (int seg = 0; seg < 3; seg++) {
        const ushort* pA = (seg == 2) ? Alo : Ahi;
        const ushort* pB = (seg == 1) ? Blo : Bhi;
#pragma unroll 1
        for (int k0 = 0; k0 < KK; k0 += BK) {
            __syncthreads(); // previous tile's reads complete
#pragma unroll
            for (int q = 0; q < NCHUNK / 4; q++) {
                const int c = q * 4 + w;
                const ushort* src;
                ushort* dst;
                if (c < 8) {
                    dst = &As[c * 512];
                    src = pA + (size_t)(row0 + c * 16 + lrow) * KK + k0 + lcol;
                } else {
                    dst = &Bs[(c - 8) * 512];
                    src = pB + (size_t)(col0 + (c - 8) * 16 + lrow) * KK + k0 + lcol;
                }
                __builtin_amdgcn_global_load_lds(
                    (const __attribute__((address_space(1))) void*)src,
                    (__attribute__((address_space(3))) void*)dst, 16, 0, 0);
            }
            __syncthreads(); // loads visible
            bf16x8 af[4], bfv[NFB];
#pragma unroll
            for (int i = 0; i < 4; i++)
                af[i] = *(const bf16x8*)&As[(wm + i * 16 + (l & 15)) * BK + (l >> 4) * 8];
#pragma unroll
            for (int j = 0; j < NFB; j++)
                bfv[j] = *(const bf16x8*)&Bs[(wn + j * 16 + (l & 15)) * BK + (l >> 4) * 8];
#pragma unroll
            for (int i = 0; i < 4; i++)
#pragma unroll
                for (int j = 0; j < NFB; j++)
                    acc[i][j] = __builtin_amdgcn_mfma_f32_16x16x32_bf16(af[i], bfv[j],
                                                                        acc[i][j], 0, 0, 0);
        }
    }
    // epilogue: D lane mapping col=lane&15, row=(lane>>4)*4+reg
#pragma unroll
    for (int i = 0; i < 4; i++) {
#pragma unroll
        for (int j = 0; j < NFB; j++) {
            const int r0 = row0 + wm + i * 16 + (l >> 4) * 4;
            const int cc = col0 + wn + j * 16 + (l & 15);
#pragma unroll
            for (int r = 0; r < 4; r++) {
                const float v = acc[i][j][r];
                const size_t off = (size_t)(r0 + r) * N + cc;
                if (SPLITOUT) {
                    const ushort h = f2bf(v);
                    Chi[off] = h;
                    Clo[off] = f2bf(v - bf2f(h));
                } else {
                    C[off] = v;
                }
            }
        }
    }
}

// ---------------- fp32 GEMM C[M,N] = A[M,K]*B[N,K]^T (kept for x_proj/dt_proj) ----
template <int EPI>
__global__ __launch_bounds__(256) void gemm_abt(const float* __restrict__ A, int lda,
                                                const float* __restrict__ B, int ldb,
                                                float* __restrict__ C,
                                                const float* __restrict__ bias,
                                                int M, int N, int K) {
    __shared__ float As[16][68];
    __shared__ float Bs[16][68];
    const int tid = threadIdx.x;
    const int row0 = blockIdx.y * 64;
    const int col0 = blockIdx.x * 64;
    const int trow = tid >> 4;
    const int tcol = tid & 15;
    const int lr = tid >> 2;
    const int lk = (tid & 3) * 4;

    float acc[4][4] = {};
    for (int k0 = 0; k0 < K; k0 += 16) {
        float4 av = *(const float4*)&A[(size_t)(row0 + lr) * lda + k0 + lk];
        float4 bv = *(const float4*)&B[(size_t)(col0 + lr) * ldb + k0 + lk];
        __syncthreads();
        As[lk + 0][lr] = av.x; As[lk + 1][lr] = av.y;
        As[lk + 2][lr] = av.z; As[lk + 3][lr] = av.w;
        Bs[lk + 0][lr] = bv.x; Bs[lk + 1][lr] = bv.y;
        Bs[lk + 2][lr] = bv.z; Bs[lk + 3][lr] = bv.w;
        __syncthreads();
#pragma unroll
        for (int k = 0; k < 16; k++) {
            float4 a4 = *(const float4*)&As[k][trow << 2];
            float4 b4 = *(const float4*)&Bs[k][tcol << 2];
            float am[4] = {a4.x, a4.y, a4.z, a4.w};
            float bn[4] = {b4.x, b4.y, b4.z, b4.w};
#pragma unroll
            for (int i = 0; i < 4; i++)
#pragma unroll
                for (int j = 0; j < 4; j++)
                    acc[i][j] = fmaf(am[i], bn[j], acc[i][j]);
        }
    }
#pragma unroll
    for (int i = 0; i < 4; i++) {
        int r = row0 + (trow << 2) + i;
        int cbase = col0 + (tcol << 2);
        float4 o;
        if (EPI == 1) {
            o.x = softplusf_(acc[i][0] + bias[cbase + 0]);
            o.y = softplusf_(acc[i][1] + bias[cbase + 1]);
            o.z = softplusf_(acc[i][2] + bias[cbase + 2]);
            o.w = softplusf_(acc[i][3] + bias[cbase + 3]);
        } else {
            o.x = acc[i][0]; o.y = acc[i][1]; o.z = acc[i][2]; o.w = acc[i][3];
        }
        *(float4*)&C[(size_t)r * N + cbase] = o;
    }
}

// ---------------- depthwise causal conv (D_CONV=4) + SiLU ----------------
__global__ __launch_bounds__(256) void conv_silu_kernel(const float* __restrict__ xin,
                                                        const float* __restrict__ cw,
                                                        const float* __restrict__ cb,
                                                        float* __restrict__ xc) {
    int idx = blockIdx.x * 256 + threadIdx.x; // NTOK*DINNER
    int ch = idx & (DINNER - 1);
    int t = idx >> 10;
    int n = t & (SEQ - 1);
    const float* base = xin + (size_t)t * DINNER + ch;
    const float* wv = cw + ch * 4;
    float acc = cb[ch];
    if (n >= 3) acc = fmaf(wv[0], base[-3 * DINNER], acc);
    if (n >= 2) acc = fmaf(wv[1], base[-2 * DINNER], acc);
    if (n >= 1) acc = fmaf(wv[2], base[-1 * DINNER], acc);
    acc = fmaf(wv[3], base[0], acc);
    xc[idx] = siluf_(acc);
}

// ---------------- selective scan, chunked ----------------
__global__ __launch_bounds__(256) void scan1_kernel(const float* __restrict__ delta,
                                                    const float* __restrict__ xc,
                                                    const float* __restrict__ dbc,
                                                    const float* __restrict__ A_log,
                                                    float* __restrict__ P,
                                                    float* __restrict__ HL) {
    int blk = blockIdx.x; // b*128 + c*4 + dg
    int dg = blk & 3;
    int c = (blk >> 2) & (NCH - 1);
    int b = blk >> 7;
    int d = dg * 256 + threadIdx.x;

    float a[DSTATE], h[DSTATE], p[DSTATE];
#pragma unroll
    for (int s = 0; s < DSTATE; s++) {
        a[s] = -__expf(A_log[d * DSTATE + s]);
        h[s] = 0.f;
        p[s] = 1.f;
    }
    int rowbase = b * SEQ + c * CHUNK;
    for (int i = 0; i < CHUNK; i++) {
        size_t row = rowbase + i;
        float dlt = delta[row * DINNER + d];
        float u = xc[row * DINNER + d];
        float du = dlt * u;
        const float* bs = dbc + row * 64 + DTRANK;
#pragma unroll
        for (int s = 0; s < DSTATE; s++) {
            float ex = __expf(dlt * a[s]);
            h[s] = fmaf(ex, h[s], du * bs[s]);
            p[s] *= ex;
        }
    }
    size_t o = ((size_t)(b * NCH + c) * DINNER + d) * DSTATE;
#pragma unroll
    for (int s = 0; s < DSTATE; s += 4) {
        *(float4*)&P[o + s] = make_float4(p[s], p[s + 1], p[s + 2], p[s + 3]);
        *(float4*)&HL[o + s] = make_float4(h[s], h[s + 1], h[s + 2], h[s + 3]);
    }
}

__global__ __launch_bounds__(256) void scan2_kernel(const float* __restrict__ P,
                                                    float* __restrict__ HL) {
    int idx = blockIdx.x * 256 + threadIdx.x; // BSZ*DINNER*DSTATE = 65536
    int b = idx >> 14;
    int ds = idx & 16383;
    float H = 0.f;
    for (int c = 0; c < NCH; c++) {
        size_t o = ((size_t)(b * NCH + c) << 14) + ds;
        float pv = P[o];
        float hl = HL[o];
        HL[o] = H;
        H = fmaf(pv, H, hl);
    }
}

// pass 3: rescan + fused epilogue; writes y as split bf16 for out_proj MFMA
__global__ __launch_bounds__(256) void scan3_kernel(const float* __restrict__ delta,
                                                    const float* __restrict__ xc,
                                                    const float* __restrict__ zbuf,
                                                    const float* __restrict__ dbc,
                                                    const float* __restrict__ A_log,
                                                    const float* __restrict__ Dp,
                                                    const float* __restrict__ HL,
                                                    ushort* __restrict__ yhi,
                                                    ushort* __restrict__ ylo) {
    int blk = blockIdx.x;
    int dg = blk & 3;
    int c = (blk >> 2) & (NCH - 1);
    int b = blk >> 7;
    int d = dg * 256 + threadIdx.x;

    float a[DSTATE], h[DSTATE];
    size_t o = ((size_t)(b * NCH + c) * DINNER + d) * DSTATE;
#pragma unroll
    for (int s = 0; s < DSTATE; s++) {
        a[s] = -__expf(A_log[d * DSTATE + s]);
        h[s] = HL[o + s];
    }
    float dd = Dp[d];
    int rowbase = b * SEQ + c * CHUNK;
    for (int i = 0; i < CHUNK; i++) {
        size_t row = rowbase + i;
        float dlt = delta[row * DINNER + d];
        float u = xc[row * DINNER + d];
        float z = zbuf[row * DINNER + d];
        float du = dlt * u;
        const float* bs = dbc + row * 64 + DTRANK;
        const float* cs = dbc + row * 64 + DTRANK + DSTATE;
        float y = 0.f;
#pragma unroll
        for (int s = 0; s < DSTATE; s++) {
            float ex = __expf(dlt * a[s]);
            h[s] = fmaf(ex, h[s], du * bs[s]);
            y = fmaf(h[s], cs[s], y);
        }
        y = fmaf(dd, u, y);
        y *= siluf_(z);
        const ushort hh = f2bf(y);
        yhi[row * DINNER + d] = hh;
        ylo[row * DINNER + d] = f2bf(y - bf2f(hh));
    }
}

// ---------------- LayerNorm + mask (reads bf16 hi/lo pair) ----------------
__global__ __launch_bounds__(256) void ln_kernel(const ushort* __restrict__ Xh,
                                                 const ushort* __restrict__ Xl,
                                                 const int* __restrict__ mask,
                                                 const float* __restrict__ nw,
                                                 const float* __restrict__ nb,
                                                 float* __restrict__ out) {
    int wave = threadIdx.x >> 6;
    int lane = threadIdx.x & 63;
    int row = blockIdx.x * 4 + wave;
    int cb = lane * 8;
    const ushort* hr = Xh + (size_t)row * DMODEL + cb;
    const ushort* lr = Xl + (size_t)row * DMODEL + cb;
    ushort4 h0 = *(const ushort4*)&hr[0];
    ushort4 h1 = *(const ushort4*)&hr[4];
    ushort4 l0 = *(const ushort4*)&lr[0];
    ushort4 l1 = *(const ushort4*)&lr[4];
    float xv[8];
    xv[0] = bf2f(h0.x) + bf2f(l0.x);
    xv[1] = bf2f(h0.y) + bf2f(l0.y);
    xv[2] = bf2f(h0.z) + bf2f(l0.z);
    xv[3] = bf2f(h0.w) + bf2f(l0.w);
    xv[4] = bf2f(h1.x) + bf2f(l1.x);
    xv[5] = bf2f(h1.y) + bf2f(l1.y);
    xv[6] = bf2f(h1.z) + bf2f(l1.z);
    xv[7] = bf2f(h1.w) + bf2f(l1.w);
    float sum = 0.f;
#pragma unroll
    for (int j = 0; j < 8; j++) sum += xv[j];
#pragma unroll
    for (int off = 32; off >= 1; off >>= 1) sum += __shfl_xor(sum, off, 64);
    float mu = sum * (1.f / DMODEL);
    float vs = 0.f;
    float dv[8];
#pragma unroll
    for (int j = 0; j < 8; j++) { dv[j] = xv[j] - mu; vs += dv[j] * dv[j]; }
#pragma unroll
    for (int off = 32; off >= 1; off >>= 1) vs += __shfl_xor(vs, off, 64);
    float sc = rsqrtf(vs * (1.f / DMODEL) + LN_EPS);
    float mk = mask[row] ? 1.f : 0.f;
    float4 w0 = *(const float4*)&nw[cb];
    float4 w1 = *(const float4*)&nw[cb + 4];
    float4 b0 = *(const float4*)&nb[cb];
    float4 b1 = *(const float4*)&nb[cb + 4];
    float4 o0, o1;
    o0.x = (dv[0] * sc * w0.x + b0.x) * mk;
    o0.y = (dv[1] * sc * w0.y + b0.y) * mk;
    o0.z = (dv[2] * sc * w0.z + b0.z) * mk;
    o0.w = (dv[3] * sc * w0.w + b0.w) * mk;
    o1.x = (dv[4] * sc * w1.x + b1.x) * mk;
    o1.y = (dv[5] * sc * w1.y + b1.y) * mk;
    o1.z = (dv[6] * sc * w1.z + b1.z) * mk;
    o1.w = (dv[7] * sc * w1.w + b1.w) * mk;
    float* orow = out + (size_t)row * DMODEL + cb;
    *(float4*)&orow[0] = o0;
    *(float4*)&orow[4] = o1;
}

extern "C" void kernel_launch(void* const* d_in, const int* in_sizes, int n_in,
                              void* d_out, int out_size, void* d_ws, size_t ws_size,
                              hipStream_t stream) {
    const float* x = (const float*)d_in[0];
    const int* mask = (const int*)d_in[1];
    const float* ipw = (const float*)d_in[2];
    const float* cw = (const float*)d_in[3];
    const float* cb = (const float*)d_in[4];
    const float* xpw = (const float*)d_in[5];
    const float* dtw = (const float*)d_in[6];
    const float* dtb = (const float*)d_in[7];
    const float* Alog = (const float*)d_in[8];
    const float* Dp = (const float*)d_in[9];
    const float* opw = (const float*)d_in[10];
    const float* nw = (const float*)d_in[11];
    const float* nb = (const float*)d_in[12];

    char* p = (char*)d_ws;
    float* xcpre = (float*)p; p += (size_t)NTOK * DINNER * 4;   // 32MB (aliased by Yhi/Ylo after conv)
    float* zbuf  = (float*)p; p += (size_t)NTOK * DINNER * 4;   // 32MB
    float* xc    = (float*)p; p += (size_t)NTOK * DINNER * 4;   // 32MB
    float* dbc   = (float*)p; p += (size_t)NTOK * 64 * 4;       // 2MB
    float* delta = (float*)p; p += (size_t)NTOK * DINNER * 4;   // 32MB
    float* P     = (float*)p; p += (size_t)BSZ * NCH * DINNER * DSTATE * 4; // 8MB
    float* HL    = (float*)p; p += (size_t)BSZ * NCH * DINNER * DSTATE * 4; // 8MB
    ushort* Xhi  = (ushort*)p; p += (size_t)NTOK * DMODEL * 2;  // 8MB
    ushort* Xlo  = (ushort*)p; p += (size_t)NTOK * DMODEL * 2;  // 8MB
    ushort* Wihi = (ushort*)p; p += (size_t)3 * 2 * DINNER * DMODEL * 2; // 6.3MB
    ushort* Wilo = (ushort*)p; p += (size_t)3 * 2 * DINNER * DMODEL * 2;
    ushort* Wohi = (ushort*)p; p += (size_t)3 * DMODEL * DINNER * 2;     // 3.1MB
    ushort* Wolo = (ushort*)p; p += (size_t)3 * DMODEL * DINNER * 2;
    ushort* Yhi = (ushort*)xcpre;               // alias: xcpre dead after conv
    ushort* Ylo = Yhi + (size_t)NTOK * DINNER;

    // weight splits (once per launch)
    split_kernel<<<(3 * 2 * DINNER * DMODEL) / 1024, 256, 0, stream>>>(ipw, Wihi, Wilo);
    split_kernel<<<(3 * DMODEL * DINNER) / 1024, 256, 0, stream>>>(opw, Wohi, Wolo);
    // x0 = mask*x, split
    mask_split_kernel<<<(NTOK * DMODEL) / 1024, 256, 0, stream>>>(x, mask, Xhi, Xlo);

    for (int l = 0; l < 3; l++) {
        const ushort* Wihi_l = Wihi + (size_t)l * 2 * DINNER * DMODEL;
        const ushort* Wilo_l = Wilo + (size_t)l * 2 * DINNER * DMODEL;
        const ushort* Wohi_l = Wohi + (size_t)l * DMODEL * DINNER;
        const ushort* Wolo_l = Wolo + (size_t)l * DMODEL * DINNER;
        const float* cw_l = cw + (size_t)l * DINNER * 4;
        const float* cb_l = cb + (size_t)l * DINNER;
        const float* xpw_l = xpw + (size_t)l * 64 * DINNER;
        const float* dtw_l = dtw + (size_t)l * DINNER * DTRANK;
        const float* dtb_l = dtb + (size_t)l * DINNER;
        const float* Alog_l = Alog + (size_t)l * DINNER * DSTATE;
        const float* Dp_l = Dp + (size_t)l * DINNER;

        // in_proj: two N=1024 halves (xc-pre and z)
        dim3 gi(DINNER / 128, NTOK / 128); // (8, 64)
        gemm_split<128, DMODEL, false><<<gi, 256, 0, stream>>>(
            Xhi, Xlo, Wihi_l, Wilo_l, xcpre, nullptr, nullptr, DINNER);
        gemm_split<128, DMODEL, false><<<gi, 256, 0, stream>>>(
            Xhi, Xlo, Wihi_l + (size_t)DINNER * DMODEL, Wilo_l + (size_t)DINNER * DMODEL,
            zbuf, nullptr, nullptr, DINNER);
        conv_silu_kernel<<<NTOK * DINNER / 256, 256, 0, stream>>>(xcpre, cw_l, cb_l, xc);
        // x_proj (fp32): dbc = xc * xpw^T
        dim3 g2(1, NTOK / 64);
        gemm_abt<0><<<g2, 256, 0, stream>>>(xc, DINNER, xpw_l, DINNER, dbc, nullptr,
                                            NTOK, 64, DINNER);
        // dt_proj (fp32) + softplus
        dim3 g3(DINNER / 64, NTOK / 64);
        gemm_abt<1><<<g3, 256, 0, stream>>>(dbc, 64, dtw_l, DTRANK, delta, dtb_l,
                                            NTOK, DINNER, DTRANK);
        scan1_kernel<<<BSZ * NCH * 4, 256, 0, stream>>>(delta, xc, dbc, Alog_l, P, HL);
        scan2_kernel<<<BSZ * DINNER * DSTATE / 256, 256, 0, stream>>>(P, HL);
        scan3_kernel<<<BSZ * NCH * 4, 256, 0, stream>>>(delta, xc, zbuf, dbc, Alog_l, Dp_l,
                                                        HL, Yhi, Ylo);
        // out_proj: MFMA, split output straight into next layer's X pair
        dim3 go(DMODEL / 64, NTOK / 128); // (8, 64)
        gemm_split<64, DINNER, true><<<go, 256, 0, stream>>>(
            Yhi, Ylo, Wohi_l, Wolo_l, nullptr, Xhi, Xlo, DMODEL);
    }
    ln_kernel<<<NTOK / 4, 256, 0, stream>>>(Xhi, Xlo, mask, nw, nb, (float*)d_out);
}

// Round 3
// 935.238 us; speedup vs baseline: 1.7563x; 1.1454x over previous
//
#include <hip/hip_runtime.h>
#include <hip/hip_bf16.h>

// Mamba backbone. Split-bf16 MFMA GEMMs (fused 3-segment) for in_proj/out_proj.
// B=4, N=2048, D_MODEL=512, D_INNER=1024, D_STATE=16, D_CONV=4, DT_RANK=32, L=3.

#define DMODEL 512
#define DINNER 1024
#define DSTATE 16
#define DTRANK 32
#define BSZ 4
#define SEQ 2048
#define NTOK (BSZ * SEQ) /* 8192 */
#define NCH 32           /* scan chunks per sequence */
#define CHUNK 64         /* SEQ / NCH */
#define LN_EPS 1e-5f

typedef __attribute__((ext_vector_type(8))) short bf16x8;
typedef __attribute__((ext_vector_type(4))) float f32x4;

__device__ __forceinline__ float siluf_(float x) { return x / (1.f + __expf(-x)); }
__device__ __forceinline__ float softplusf_(float x) {
    return fmaxf(x, 0.f) + log1pf(__expf(-fabsf(x)));
}
__device__ __forceinline__ ushort f2bf(float f) {
    unsigned u = __float_as_uint(f);
    u += 0x7fffu + ((u >> 16) & 1u);
    return (ushort)(u >> 16);
}
__device__ __forceinline__ float bf2f(ushort h) {
    return __uint_as_float((unsigned)h << 16);
}

// ---------------- fp32 -> (hi,lo) bf16 split, 4 elems/thread ----------------
__global__ __launch_bounds__(256) void split_kernel(const float* __restrict__ x,
                                                    ushort* __restrict__ hi,
                                                    ushort* __restrict__ lo) {
    int i = blockIdx.x * 256 + threadIdx.x;
    float4 v = ((const float4*)x)[i];
    ushort4 h, l;
    h.x = f2bf(v.x); l.x = f2bf(v.x - bf2f(h.x));
    h.y = f2bf(v.y); l.y = f2bf(v.y - bf2f(h.y));
    h.z = f2bf(v.z); l.z = f2bf(v.z - bf2f(h.z));
    h.w = f2bf(v.w); l.w = f2bf(v.w - bf2f(h.w));
    ((ushort4*)hi)[i] = h;
    ((ushort4*)lo)[i] = l;
}

// ---------------- mask * x, fused split ----------------
__global__ __launch_bounds__(256) void mask_split_kernel(const float* __restrict__ x,
                                                         const int* __restrict__ mask,
                                                         ushort* __restrict__ hi,
                                                         ushort* __restrict__ lo) {
    int i = blockIdx.x * 256 + threadIdx.x; // 4-elem groups; 128 groups per row
    int row = i >> 7;
    float4 v = ((const float4*)x)[i];
    if (!mask[row]) { v.x = 0.f; v.y = 0.f; v.z = 0.f; v.w = 0.f; }
    ushort4 h, l;
    h.x = f2bf(v.x); l.x = f2bf(v.x - bf2f(h.x));
    h.y = f2bf(v.y); l.y = f2bf(v.y - bf2f(h.y));
    h.z = f2bf(v.z); l.z = f2bf(v.z - bf2f(h.z));
    h.w = f2bf(v.w); l.w = f2bf(v.w - bf2f(h.w));
    ((ushort4*)hi)[i] = h;
    ((ushort4*)lo)[i] = l;
}

// ---------------- split-bf16 MFMA GEMM, fused 3-segment ----------------
// C[M,N] = (Ahi+Alo)[M,KK] * (Bhi+Blo)[N,KK]^T, computed as
// Ahi*Bhi + Ahi*Blo + Alo*Bhi in ONE K-pass (all 4 tiles staged per k-step).
// BM=BN=128, BK=32, 4 waves each owning a 64x64 quadrant.
// XCD-chunked block swizzle: requires gridDim.x*gridDim.y % 8 == 0.
// SPLITOUT: write C as bf16 (hi,lo) pair instead of fp32.
template <bool SPLITOUT>
__global__ __launch_bounds__(256) void gemm_split3(
    const ushort* __restrict__ Ahi, const ushort* __restrict__ Alo,
    const ushort* __restrict__ Bhi, const ushort* __restrict__ Blo,
    float* __restrict__ C, ushort* __restrict__ Chi, ushort* __restrict__ Clo,
    int N, int KK) {
    constexpr int BM = 128, BN = 128, BK = 32;
    __shared__ ushort As[2][BM * BK]; // [0]=hi [1]=lo, 8KB each
    __shared__ ushort Bs[2][BN * BK];
    const int tid = threadIdx.x;
    const int w = tid >> 6, l = tid & 63;
    // bijective chunked XCD swizzle: XCD k gets contiguous logical tile range
    const int gx = gridDim.x;
    const int nwg = gx * gridDim.y;
    const int linear = blockIdx.y * gx + blockIdx.x;
    const int logical = (linear & 7) * (nwg >> 3) + (linear >> 3);
    const int bx = logical % gx;
    const int by = logical / gx;
    const int row0 = by * BM, col0 = bx * BN;
    const int wm = (w >> 1) * 64, wn = (w & 1) * 64;
    const int lrow = l >> 2, lcol = (l & 3) * 8; // staging: 16 rows x 32 cols / chunk
    const int l15 = l & 15, lk8 = (l >> 4) * 8;  // fragment addressing

    f32x4 acc[4][4];
#pragma unroll
    for (int i = 0; i < 4; i++)
#pragma unroll
        for (int j = 0; j < 4; j++)
#pragma unroll
            for (int r = 0; r < 4; r++) acc[i][j][r] = 0.f;

#pragma unroll 1
    for (int k0 = 0; k0 < KK; k0 += BK) {
        __syncthreads(); // previous tile's reads complete
#pragma unroll
        for (int q = 0; q < 8; q++) {
            const int c = q * 4 + w; // 0..31, wave-uniform
            const int sub = c & 7;
            const ushort* src;
            ushort* dst;
            if (c < 8) {
                src = Ahi + (size_t)(row0 + sub * 16 + lrow) * KK + k0 + lcol;
                dst = &As[0][sub * 512];
            } else if (c < 16) {
                src = Alo + (size_t)(row0 + sub * 16 + lrow) * KK + k0 + lcol;
                dst = &As[1][sub * 512];
            } else if (c < 24) {
                src = Bhi + (size_t)(col0 + sub * 16 + lrow) * KK + k0 + lcol;
                dst = &Bs[0][sub * 512];
            } else {
                src = Blo + (size_t)(col0 + sub * 16 + lrow) * KK + k0 + lcol;
                dst = &Bs[1][sub * 512];
            }
            __builtin_amdgcn_global_load_lds(
                (const __attribute__((address_space(1))) void*)src,
                (__attribute__((address_space(3))) void*)dst, 16, 0, 0);
        }
        __syncthreads(); // loads visible
        bf16x8 ah[4], al[4], bh[4], bl[4];
#pragma unroll
        for (int i = 0; i < 4; i++) {
            ah[i] = *(const bf16x8*)&As[0][(wm + i * 16 + l15) * BK + lk8];
            al[i] = *(const bf16x8*)&As[1][(wm + i * 16 + l15) * BK + lk8];
            bh[i] = *(const bf16x8*)&Bs[0][(wn + i * 16 + l15) * BK + lk8];
            bl[i] = *(const bf16x8*)&Bs[1][(wn + i * 16 + l15) * BK + lk8];
        }
#pragma unroll
        for (int i = 0; i < 4; i++)
#pragma unroll
            for (int j = 0; j < 4; j++) {
                acc[i][j] = __builtin_amdgcn_mfma_f32_16x16x32_bf16(ah[i], bh[j], acc[i][j], 0, 0, 0);
                acc[i][j] = __builtin_amdgcn_mfma_f32_16x16x32_bf16(ah[i], bl[j], acc[i][j], 0, 0, 0);
                acc[i][j] = __builtin_amdgcn_mfma_f32_16x16x32_bf16(al[i], bh[j], acc[i][j], 0, 0, 0);
            }
    }
    // epilogue: D lane mapping col=lane&15, row=(lane>>4)*4+reg
#pragma unroll
    for (int i = 0; i < 4; i++) {
#pragma unroll
        for (int j = 0; j < 4; j++) {
            const int r0 = row0 + wm + i * 16 + (l >> 4) * 4;
            const int cc = col0 + wn + j * 16 + l15;
#pragma unroll
            for (int r = 0; r < 4; r++) {
                const float v = acc[i][j][r];
                const size_t off = (size_t)(r0 + r) * N + cc;
                if (SPLITOUT) {
                    const ushort h = f2bf(v);
                    Chi[off] = h;
                    Clo[off] = f2bf(v - bf2f(h));
                } else {
                    C[off] = v;
                }
            }
        }
    }
}

// ---------------- fp32 GEMM C[M,N] = A[M,K]*B[N,K]^T (x_proj/dt_proj) ----
template <int EPI>
__global__ __launch_bounds__(256) void gemm_abt(const float* __restrict__ A, int lda,
                                                const float* __restrict__ B, int ldb,
                                                float* __restrict__ C,
                                                const float* __restrict__ bias,
                                                int M, int N, int K) {
    __shared__ float As[16][68];
    __shared__ float Bs[16][68];
    const int tid = threadIdx.x;
    const int row0 = blockIdx.y * 64;
    const int col0 = blockIdx.x * 64;
    const int trow = tid >> 4;
    const int tcol = tid & 15;
    const int lr = tid >> 2;
    const int lk = (tid & 3) * 4;

    float acc[4][4] = {};
    for (int k0 = 0; k0 < K; k0 += 16) {
        float4 av = *(const float4*)&A[(size_t)(row0 + lr) * lda + k0 + lk];
        float4 bv = *(const float4*)&B[(size_t)(col0 + lr) * ldb + k0 + lk];
        __syncthreads();
        As[lk + 0][lr] = av.x; As[lk + 1][lr] = av.y;
        As[lk + 2][lr] = av.z; As[lk + 3][lr] = av.w;
        Bs[lk + 0][lr] = bv.x; Bs[lk + 1][lr] = bv.y;
        Bs[lk + 2][lr] = bv.z; Bs[lk + 3][lr] = bv.w;
        __syncthreads();
#pragma unroll
        for (int k = 0; k < 16; k++) {
            float4 a4 = *(const float4*)&As[k][trow << 2];
            float4 b4 = *(const float4*)&Bs[k][tcol << 2];
            float am[4] = {a4.x, a4.y, a4.z, a4.w};
            float bn[4] = {b4.x, b4.y, b4.z, b4.w};
#pragma unroll
            for (int i = 0; i < 4; i++)
#pragma unroll
                for (int j = 0; j < 4; j++)
                    acc[i][j] = fmaf(am[i], bn[j], acc[i][j]);
        }
    }
#pragma unroll
    for (int i = 0; i < 4; i++) {
        int r = row0 + (trow << 2) + i;
        int cbase = col0 + (tcol << 2);
        float4 o;
        if (EPI == 1) {
            o.x = softplusf_(acc[i][0] + bias[cbase + 0]);
            o.y = softplusf_(acc[i][1] + bias[cbase + 1]);
            o.z = softplusf_(acc[i][2] + bias[cbase + 2]);
            o.w = softplusf_(acc[i][3] + bias[cbase + 3]);
        } else {
            o.x = acc[i][0]; o.y = acc[i][1]; o.z = acc[i][2]; o.w = acc[i][3];
        }
        *(float4*)&C[(size_t)r * N + cbase] = o;
    }
}

// ---------------- depthwise causal conv (D_CONV=4) + SiLU ----------------
__global__ __launch_bounds__(256) void conv_silu_kernel(const float* __restrict__ xin,
                                                        const float* __restrict__ cw,
                                                        const float* __restrict__ cb,
                                                        float* __restrict__ xc) {
    int idx = blockIdx.x * 256 + threadIdx.x; // NTOK*DINNER
    int ch = idx & (DINNER - 1);
    int t = idx >> 10;
    int n = t & (SEQ - 1);
    const float* base = xin + (size_t)t * DINNER + ch;
    const float* wv = cw + ch * 4;
    float acc = cb[ch];
    if (n >= 3) acc = fmaf(wv[0], base[-3 * DINNER], acc);
    if (n >= 2) acc = fmaf(wv[1], base[-2 * DINNER], acc);
    if (n >= 1) acc = fmaf(wv[2], base[-1 * DINNER], acc);
    acc = fmaf(wv[3], base[0], acc);
    xc[idx] = siluf_(acc);
}

// ---------------- selective scan, chunked ----------------
__global__ __launch_bounds__(256) void scan1_kernel(const float* __restrict__ delta,
                                                    const float* __restrict__ xc,
                                                    const float* __restrict__ dbc,
                                                    const float* __restrict__ A_log,
                                                    float* __restrict__ P,
                                                    float* __restrict__ HL) {
    int blk = blockIdx.x; // b*128 + c*4 + dg
    int dg = blk & 3;
    int c = (blk >> 2) & (NCH - 1);
    int b = blk >> 7;
    int d = dg * 256 + threadIdx.x;

    float a[DSTATE], h[DSTATE], p[DSTATE];
#pragma unroll
    for (int s = 0; s < DSTATE; s++) {
        a[s] = -__expf(A_log[d * DSTATE + s]);
        h[s] = 0.f;
        p[s] = 1.f;
    }
    int rowbase = b * SEQ + c * CHUNK;
    for (int i = 0; i < CHUNK; i++) {
        size_t row = rowbase + i;
        float dlt = delta[row * DINNER + d];
        float u = xc[row * DINNER + d];
        float du = dlt * u;
        const float* bs = dbc + row * 64 + DTRANK;
#pragma unroll
        for (int s = 0; s < DSTATE; s++) {
            float ex = __expf(dlt * a[s]);
            h[s] = fmaf(ex, h[s], du * bs[s]);
            p[s] *= ex;
        }
    }
    size_t o = ((size_t)(b * NCH + c) * DINNER + d) * DSTATE;
#pragma unroll
    for (int s = 0; s < DSTATE; s += 4) {
        *(float4*)&P[o + s] = make_float4(p[s], p[s + 1], p[s + 2], p[s + 3]);
        *(float4*)&HL[o + s] = make_float4(h[s], h[s + 1], h[s + 2], h[s + 3]);
    }
}

__global__ __launch_bounds__(256) void scan2_kernel(const float* __restrict__ P,
                                                    float* __restrict__ HL) {
    int idx = blockIdx.x * 256 + threadIdx.x; // BSZ*DINNER*DSTATE = 65536
    int b = idx >> 14;
    int ds = idx & 16383;
    float H = 0.f;
    for (int c = 0; c < NCH; c++) {
        size_t o = ((size_t)(b * NCH + c) << 14) + ds;
        float pv = P[o];
        float hl = HL[o];
        HL[o] = H;
        H = fmaf(pv, H, hl);
    }
}

// pass 3: rescan + fused epilogue; writes y as split bf16 for out_proj MFMA
__global__ __launch_bounds__(256) void scan3_kernel(const float* __restrict__ delta,
                                                    const float* __restrict__ xc,
                                                    const float* __restrict__ zbuf,
                                                    const float* __restrict__ dbc,
                                                    const float* __restrict__ A_log,
                                                    const float* __restrict__ Dp,
                                                    const float* __restrict__ HL,
                                                    ushort* __restrict__ yhi,
                                                    ushort* __restrict__ ylo) {
    int blk = blockIdx.x;
    int dg = blk & 3;
    int c = (blk >> 2) & (NCH - 1);
    int b = blk >> 7;
    int d = dg * 256 + threadIdx.x;

    float a[DSTATE], h[DSTATE];
    size_t o = ((size_t)(b * NCH + c) * DINNER + d) * DSTATE;
#pragma unroll
    for (int s = 0; s < DSTATE; s++) {
        a[s] = -__expf(A_log[d * DSTATE + s]);
        h[s] = HL[o + s];
    }
    float dd = Dp[d];
    int rowbase = b * SEQ + c * CHUNK;
    for (int i = 0; i < CHUNK; i++) {
        size_t row = rowbase + i;
        float dlt = delta[row * DINNER + d];
        float u = xc[row * DINNER + d];
        float z = zbuf[row * DINNER + d];
        float du = dlt * u;
        const float* bs = dbc + row * 64 + DTRANK;
        const float* cs = dbc + row * 64 + DTRANK + DSTATE;
        float y = 0.f;
#pragma unroll
        for (int s = 0; s < DSTATE; s++) {
            float ex = __expf(dlt * a[s]);
            h[s] = fmaf(ex, h[s], du * bs[s]);
            y = fmaf(h[s], cs[s], y);
        }
        y = fmaf(dd, u, y);
        y *= siluf_(z);
        const ushort hh = f2bf(y);
        yhi[row * DINNER + d] = hh;
        ylo[row * DINNER + d] = f2bf(y - bf2f(hh));
    }
}

// ---------------- LayerNorm + mask (reads bf16 hi/lo pair) ----------------
__global__ __launch_bounds__(256) void ln_kernel(const ushort* __restrict__ Xh,
                                                 const ushort* __restrict__ Xl,
                                                 const int* __restrict__ mask,
                                                 const float* __restrict__ nw,
                                                 const float* __restrict__ nb,
                                                 float* __restrict__ out) {
    int wave = threadIdx.x >> 6;
    int lane = threadIdx.x & 63;
    int row = blockIdx.x * 4 + wave;
    int cb = lane * 8;
    const ushort* hr = Xh + (size_t)row * DMODEL + cb;
    const ushort* lr = Xl + (size_t)row * DMODEL + cb;
    ushort4 h0 = *(const ushort4*)&hr[0];
    ushort4 h1 = *(const ushort4*)&hr[4];
    ushort4 l0 = *(const ushort4*)&lr[0];
    ushort4 l1 = *(const ushort4*)&lr[4];
    float xv[8];
    xv[0] = bf2f(h0.x) + bf2f(l0.x);
    xv[1] = bf2f(h0.y) + bf2f(l0.y);
    xv[2] = bf2f(h0.z) + bf2f(l0.z);
    xv[3] = bf2f(h0.w) + bf2f(l0.w);
    xv[4] = bf2f(h1.x) + bf2f(l1.x);
    xv[5] = bf2f(h1.y) + bf2f(l1.y);
    xv[6] = bf2f(h1.z) + bf2f(l1.z);
    xv[7] = bf2f(h1.w) + bf2f(l1.w);
    float sum = 0.f;
#pragma unroll
    for (int j = 0; j < 8; j++) sum += xv[j];
#pragma unroll
    for (int off = 32; off >= 1; off >>= 1) sum += __shfl_xor(sum, off, 64);
    float mu = sum * (1.f / DMODEL);
    float vs = 0.f;
    float dv[8];
#pragma unroll
    for (int j = 0; j < 8; j++) { dv[j] = xv[j] - mu; vs += dv[j] * dv[j]; }
#pragma unroll
    for (int off = 32; off >= 1; off >>= 1) vs += __shfl_xor(vs, off, 64);
    float sc = rsqrtf(vs * (1.f / DMODEL) + LN_EPS);
    float mk = mask[row] ? 1.f : 0.f;
    float4 w0 = *(const float4*)&nw[cb];
    float4 w1 = *(const float4*)&nw[cb + 4];
    float4 b0 = *(const float4*)&nb[cb];
    float4 b1 = *(const float4*)&nb[cb + 4];
    float4 o0, o1;
    o0.x = (dv[0] * sc * w0.x + b0.x) * mk;
    o0.y = (dv[1] * sc * w0.y + b0.y) * mk;
    o0.z = (dv[2] * sc * w0.z + b0.z) * mk;
    o0.w = (dv[3] * sc * w0.w + b0.w) * mk;
    o1.x = (dv[4] * sc * w1.x + b1.x) * mk;
    o1.y = (dv[5] * sc * w1.y + b1.y) * mk;
    o1.z = (dv[6] * sc * w1.z + b1.z) * mk;
    o1.w = (dv[7] * sc * w1.w + b1.w) * mk;
    float* orow = out + (size_t)row * DMODEL + cb;
    *(float4*)&orow[0] = o0;
    *(float4*)&orow[4] = o1;
}

extern "C" void kernel_launch(void* const* d_in, const int* in_sizes, int n_in,
                              void* d_out, int out_size, void* d_ws, size_t ws_size,
                              hipStream_t stream) {
    const float* x = (const float*)d_in[0];
    const int* mask = (const int*)d_in[1];
    const float* ipw = (const float*)d_in[2];
    const float* cw = (const float*)d_in[3];
    const float* cb = (const float*)d_in[4];
    const float* xpw = (const float*)d_in[5];
    const float* dtw = (const float*)d_in[6];
    const float* dtb = (const float*)d_in[7];
    const float* Alog = (const float*)d_in[8];
    const float* Dp = (const float*)d_in[9];
    const float* opw = (const float*)d_in[10];
    const float* nw = (const float*)d_in[11];
    const float* nb = (const float*)d_in[12];

    char* p = (char*)d_ws;
    float* xcpre = (float*)p; p += (size_t)NTOK * DINNER * 4;   // 32MB (aliased by Yhi/Ylo after conv)
    float* zbuf  = (float*)p; p += (size_t)NTOK * DINNER * 4;   // 32MB
    float* xc    = (float*)p; p += (size_t)NTOK * DINNER * 4;   // 32MB
    float* dbc   = (float*)p; p += (size_t)NTOK * 64 * 4;       // 2MB
    float* delta = (float*)p; p += (size_t)NTOK * DINNER * 4;   // 32MB
    float* P     = (float*)p; p += (size_t)BSZ * NCH * DINNER * DSTATE * 4; // 8MB
    float* HL    = (float*)p; p += (size_t)BSZ * NCH * DINNER * DSTATE * 4; // 8MB
    ushort* Xhi  = (ushort*)p; p += (size_t)NTOK * DMODEL * 2;  // 8MB
    ushort* Xlo  = (ushort*)p; p += (size_t)NTOK * DMODEL * 2;  // 8MB
    ushort* Wihi = (ushort*)p; p += (size_t)3 * 2 * DINNER * DMODEL * 2; // 6.3MB
    ushort* Wilo = (ushort*)p; p += (size_t)3 * 2 * DINNER * DMODEL * 2;
    ushort* Wohi = (ushort*)p; p += (size_t)3 * DMODEL * DINNER * 2;     // 3.1MB
    ushort* Wolo = (ushort*)p; p += (size_t)3 * DMODEL * DINNER * 2;
    ushort* Yhi = (ushort*)xcpre;               // alias: xcpre dead after conv
    ushort* Ylo = Yhi + (size_t)NTOK * DINNER;

    // weight splits (once per launch)
    split_kernel<<<(3 * 2 * DINNER * DMODEL) / 1024, 256, 0, stream>>>(ipw, Wihi, Wilo);
    split_kernel<<<(3 * DMODEL * DINNER) / 1024, 256, 0, stream>>>(opw, Wohi, Wolo);
    // x0 = mask*x, split
    mask_split_kernel<<<(NTOK * DMODEL) / 1024, 256, 0, stream>>>(x, mask, Xhi, Xlo);

    for (int l = 0; l < 3; l++) {
        const ushort* Wihi_l = Wihi + (size_t)l * 2 * DINNER * DMODEL;
        const ushort* Wilo_l = Wilo + (size_t)l * 2 * DINNER * DMODEL;
        const ushort* Wohi_l = Wohi + (size_t)l * DMODEL * DINNER;
        const ushort* Wolo_l = Wolo + (size_t)l * DMODEL * DINNER;
        const float* cw_l = cw + (size_t)l * DINNER * 4;
        const float* cb_l = cb + (size_t)l * DINNER;
        const float* xpw_l = xpw + (size_t)l * 64 * DINNER;
        const float* dtw_l = dtw + (size_t)l * DINNER * DTRANK;
        const float* dtb_l = dtb + (size_t)l * DINNER;
        const float* Alog_l = Alog + (size_t)l * DINNER * DSTATE;
        const float* Dp_l = Dp + (size_t)l * DINNER;

        // in_proj: two N=1024 halves (xc-pre and z), fused 3-segment MFMA
        dim3 gi(DINNER / 128, NTOK / 128); // (8, 64) -> 512 blocks, %8==0
        gemm_split3<false><<<gi, 256, 0, stream>>>(
            Xhi, Xlo, Wihi_l, Wilo_l, xcpre, nullptr, nullptr, DINNER, DMODEL);
        gemm_split3<false><<<gi, 256, 0, stream>>>(
            Xhi, Xlo, Wihi_l + (size_t)DINNER * DMODEL, Wilo_l + (size_t)DINNER * DMODEL,
            zbuf, nullptr, nullptr, DINNER, DMODEL);
        conv_silu_kernel<<<NTOK * DINNER / 256, 256, 0, stream>>>(xcpre, cw_l, cb_l, xc);
        // x_proj (fp32): dbc = xc * xpw^T
        dim3 g2(1, NTOK / 64);
        gemm_abt<0><<<g2, 256, 0, stream>>>(xc, DINNER, xpw_l, DINNER, dbc, nullptr,
                                            NTOK, 64, DINNER);
        // dt_proj (fp32) + softplus
        dim3 g3(DINNER / 64, NTOK / 64);
        gemm_abt<1><<<g3, 256, 0, stream>>>(dbc, 64, dtw_l, DTRANK, delta, dtb_l,
                                            NTOK, DINNER, DTRANK);
        scan1_kernel<<<BSZ * NCH * 4, 256, 0, stream>>>(delta, xc, dbc, Alog_l, P, HL);
        scan2_kernel<<<BSZ * DINNER * DSTATE / 256, 256, 0, stream>>>(P, HL);
        scan3_kernel<<<BSZ * NCH * 4, 256, 0, stream>>>(delta, xc, zbuf, dbc, Alog_l, Dp_l,
                                                        HL, Yhi, Ylo);
        // out_proj: fused MFMA, split output straight into next layer's X pair
        dim3 go(DMODEL / 128, NTOK / 128); // (4, 64) -> 256 blocks, %8==0
        gemm_split3<true><<<go, 256, 0, stream>>>(
            Yhi, Ylo, Wohi_l, Wolo_l, nullptr, Xhi, Xlo, DMODEL, DINNER);
    }
    ln_kernel<<<NTOK / 4, 256, 0, stream>>>(Xhi, Xlo, mask, nw, nb, (float*)d_out);
}

// Round 4
// 851.014 us; speedup vs baseline: 1.9301x; 1.0990x over previous
//
#include <hip/hip_runtime.h>
#include <hip/hip_bf16.h>

// Mamba backbone. Split-bf16 MFMA GEMMs (fused 3-segment) for in_proj/out_proj,
// split-K MFMA x_proj with in-kernel fp32->bf16hi/lo staging.
// B=4, N=2048, D_MODEL=512, D_INNER=1024, D_STATE=16, D_CONV=4, DT_RANK=32, L=3.

#define DMODEL 512
#define DINNER 1024
#define DSTATE 16
#define DTRANK 32
#define BSZ 4
#define SEQ 2048
#define NTOK (BSZ * SEQ) /* 8192 */
#define NCH 32           /* scan chunks per sequence */
#define CHUNK 64         /* SEQ / NCH */
#define LN_EPS 1e-5f
#define XP_KS 8          /* x_proj split-K slices */

typedef __attribute__((ext_vector_type(8))) short bf16x8;
typedef __attribute__((ext_vector_type(4))) float f32x4;

__device__ __forceinline__ float siluf_(float x) { return x / (1.f + __expf(-x)); }
__device__ __forceinline__ float softplusf_(float x) {
    return fmaxf(x, 0.f) + log1pf(__expf(-fabsf(x)));
}
__device__ __forceinline__ ushort f2bf(float f) {
    unsigned u = __float_as_uint(f);
    u += 0x7fffu + ((u >> 16) & 1u);
    return (ushort)(u >> 16);
}
__device__ __forceinline__ float bf2f(ushort h) {
    return __uint_as_float((unsigned)h << 16);
}

// ---------------- fp32 -> (hi,lo) bf16 split, 4 elems/thread ----------------
__global__ __launch_bounds__(256) void split_kernel(const float* __restrict__ x,
                                                    ushort* __restrict__ hi,
                                                    ushort* __restrict__ lo) {
    int i = blockIdx.x * 256 + threadIdx.x;
    float4 v = ((const float4*)x)[i];
    ushort4 h, l;
    h.x = f2bf(v.x); l.x = f2bf(v.x - bf2f(h.x));
    h.y = f2bf(v.y); l.y = f2bf(v.y - bf2f(h.y));
    h.z = f2bf(v.z); l.z = f2bf(v.z - bf2f(h.z));
    h.w = f2bf(v.w); l.w = f2bf(v.w - bf2f(h.w));
    ((ushort4*)hi)[i] = h;
    ((ushort4*)lo)[i] = l;
}

// ---------------- mask * x, fused split ----------------
__global__ __launch_bounds__(256) void mask_split_kernel(const float* __restrict__ x,
                                                         const int* __restrict__ mask,
                                                         ushort* __restrict__ hi,
                                                         ushort* __restrict__ lo) {
    int i = blockIdx.x * 256 + threadIdx.x;
    int row = i >> 7;
    float4 v = ((const float4*)x)[i];
    if (!mask[row]) { v.x = 0.f; v.y = 0.f; v.z = 0.f; v.w = 0.f; }
    ushort4 h, l;
    h.x = f2bf(v.x); l.x = f2bf(v.x - bf2f(h.x));
    h.y = f2bf(v.y); l.y = f2bf(v.y - bf2f(h.y));
    h.z = f2bf(v.z); l.z = f2bf(v.z - bf2f(h.z));
    h.w = f2bf(v.w); l.w = f2bf(v.w - bf2f(h.w));
    ((ushort4*)hi)[i] = h;
    ((ushort4*)lo)[i] = l;
}

// ---------------- split-bf16 MFMA GEMM, fused 3-segment ----------------
// C[M,N] = (Ahi+Alo)[M,KK] * (Bhi+Blo)[N,KK]^T, one K-pass, 3 MFMAs/frag-pair.
// BM=BN=128, BK=32, 4 waves each owning a 64x64 quadrant.
// gridDim.z=2 selects B row-panel (+Bz_off) and C vs Cz destination (in_proj merge).
template <bool SPLITOUT>
__global__ __launch_bounds__(256) void gemm_split3(
    const ushort* __restrict__ Ahi, const ushort* __restrict__ Alo,
    const ushort* __restrict__ Bhi, const ushort* __restrict__ Blo,
    float* __restrict__ C, float* __restrict__ Cz, size_t Bz_off,
    ushort* __restrict__ Chi, ushort* __restrict__ Clo,
    int N, int KK) {
    constexpr int BM = 128, BN = 128, BK = 32;
    __shared__ ushort As[2][BM * BK]; // [0]=hi [1]=lo, 8KB each
    __shared__ ushort Bs[2][BN * BK];
    const int tid = threadIdx.x;
    const int w = tid >> 6, l = tid & 63;
    const size_t boff = (size_t)blockIdx.z * Bz_off;
    const ushort* Bhi_p = Bhi + boff;
    const ushort* Blo_p = Blo + boff;
    float* Cdst = blockIdx.z ? Cz : C;
    // bijective chunked XCD swizzle (per z-slice; nwg % 8 == 0)
    const int gx = gridDim.x;
    const int nwg = gx * gridDim.y;
    const int linear = blockIdx.y * gx + blockIdx.x;
    const int logical = (linear & 7) * (nwg >> 3) + (linear >> 3);
    const int bx = logical % gx;
    const int by = logical / gx;
    const int row0 = by * BM, col0 = bx * BN;
    const int wm = (w >> 1) * 64, wn = (w & 1) * 64;
    const int lrow = l >> 2, lcol = (l & 3) * 8;
    const int l15 = l & 15, lk8 = (l >> 4) * 8;

    f32x4 acc[4][4];
#pragma unroll
    for (int i = 0; i < 4; i++)
#pragma unroll
        for (int j = 0; j < 4; j++)
#pragma unroll
            for (int r = 0; r < 4; r++) acc[i][j][r] = 0.f;

#pragma unroll 1
    for (int k0 = 0; k0 < KK; k0 += BK) {
        __syncthreads();
#pragma unroll
        for (int q = 0; q < 8; q++) {
            const int c = q * 4 + w;
            const int sub = c & 7;
            const ushort* src;
            ushort* dst;
            if (c < 8) {
                src = Ahi + (size_t)(row0 + sub * 16 + lrow) * KK + k0 + lcol;
                dst = &As[0][sub * 512];
            } else if (c < 16) {
                src = Alo + (size_t)(row0 + sub * 16 + lrow) * KK + k0 + lcol;
                dst = &As[1][sub * 512];
            } else if (c < 24) {
                src = Bhi_p + (size_t)(col0 + sub * 16 + lrow) * KK + k0 + lcol;
                dst = &Bs[0][sub * 512];
            } else {
                src = Blo_p + (size_t)(col0 + sub * 16 + lrow) * KK + k0 + lcol;
                dst = &Bs[1][sub * 512];
            }
            __builtin_amdgcn_global_load_lds(
                (const __attribute__((address_space(1))) void*)src,
                (__attribute__((address_space(3))) void*)dst, 16, 0, 0);
        }
        __syncthreads();
        bf16x8 ah[4], al[4], bh[4], bl[4];
#pragma unroll
        for (int i = 0; i < 4; i++) {
            ah[i] = *(const bf16x8*)&As[0][(wm + i * 16 + l15) * BK + lk8];
            al[i] = *(const bf16x8*)&As[1][(wm + i * 16 + l15) * BK + lk8];
            bh[i] = *(const bf16x8*)&Bs[0][(wn + i * 16 + l15) * BK + lk8];
            bl[i] = *(const bf16x8*)&Bs[1][(wn + i * 16 + l15) * BK + lk8];
        }
#pragma unroll
        for (int i = 0; i < 4; i++)
#pragma unroll
            for (int j = 0; j < 4; j++) {
                acc[i][j] = __builtin_amdgcn_mfma_f32_16x16x32_bf16(ah[i], bh[j], acc[i][j], 0, 0, 0);
                acc[i][j] = __builtin_amdgcn_mfma_f32_16x16x32_bf16(ah[i], bl[j], acc[i][j], 0, 0, 0);
                acc[i][j] = __builtin_amdgcn_mfma_f32_16x16x32_bf16(al[i], bh[j], acc[i][j], 0, 0, 0);
            }
    }
#pragma unroll
    for (int i = 0; i < 4; i++) {
#pragma unroll
        for (int j = 0; j < 4; j++) {
            const int r0 = row0 + wm + i * 16 + (l >> 4) * 4;
            const int cc = col0 + wn + j * 16 + l15;
#pragma unroll
            for (int r = 0; r < 4; r++) {
                const float v = acc[i][j][r];
                const size_t off = (size_t)(r0 + r) * N + cc;
                if (SPLITOUT) {
                    const ushort h = f2bf(v);
                    Chi[off] = h;
                    Clo[off] = f2bf(v - bf2f(h));
                } else {
                    Cdst[off] = v;
                }
            }
        }
    }
}

// ---------------- x_proj: split-K split-bf16 MFMA, reg-staged conversion -------
// dbc_part[ks][NTOK][64] += xc[rows, ks-slice] * xpw[64, ks-slice]^T (3-segment).
// Grid (XP_KS, NTOK/128). A=xc fp32, B=xpw fp32; both converted to hi/lo in regs.
__global__ __launch_bounds__(256) void xproj_mfma(const float* __restrict__ A,
                                                  const float* __restrict__ Bw,
                                                  float* __restrict__ part) {
    constexpr int BK = 32, KS_LEN = DINNER / XP_KS; // 128
    __shared__ ushort As0[128 * 32], As1[128 * 32]; // 8KB each
    __shared__ ushort Bs0[64 * 32], Bs1[64 * 32];   // 4KB each
    const int tid = threadIdx.x;
    const int w = tid >> 6, l = tid & 63;
    const int ks = blockIdx.x;
    const int row0 = blockIdx.y * 128;
    const int wm = (w >> 1) * 64, wn = (w & 1) * 32;
    const int l15 = l & 15, lk8 = (l >> 4) * 8;

    f32x4 acc[4][2];
#pragma unroll
    for (int i = 0; i < 4; i++)
#pragma unroll
        for (int j = 0; j < 2; j++)
#pragma unroll
            for (int r = 0; r < 4; r++) acc[i][j][r] = 0.f;

    const int c0 = (tid & 3) * 8;
#pragma unroll 1
    for (int k0 = 0; k0 < KS_LEN; k0 += BK) {
        const int kbase = ks * KS_LEN + k0;
        __syncthreads();
        // stage A: 128 rows x 32 cols fp32 -> hi/lo bf16
#pragma unroll
        for (int it = 0; it < 2; it++) {
            const int r = (tid >> 2) + it * 64;
            const float* src = A + (size_t)(row0 + r) * DINNER + kbase + c0;
            float4 v0 = *(const float4*)src;
            float4 v1 = *(const float4*)(src + 4);
            float vv[8] = {v0.x, v0.y, v0.z, v0.w, v1.x, v1.y, v1.z, v1.w};
            ushort4 h0, h1, l0, l1;
            h0.x = f2bf(vv[0]); l0.x = f2bf(vv[0] - bf2f(h0.x));
            h0.y = f2bf(vv[1]); l0.y = f2bf(vv[1] - bf2f(h0.y));
            h0.z = f2bf(vv[2]); l0.z = f2bf(vv[2] - bf2f(h0.z));
            h0.w = f2bf(vv[3]); l0.w = f2bf(vv[3] - bf2f(h0.w));
            h1.x = f2bf(vv[4]); l1.x = f2bf(vv[4] - bf2f(h1.x));
            h1.y = f2bf(vv[5]); l1.y = f2bf(vv[5] - bf2f(h1.y));
            h1.z = f2bf(vv[6]); l1.z = f2bf(vv[6] - bf2f(h1.z));
            h1.w = f2bf(vv[7]); l1.w = f2bf(vv[7] - bf2f(h1.w));
            *(ushort4*)&As0[r * 32 + c0] = h0;
            *(ushort4*)&As0[r * 32 + c0 + 4] = h1;
            *(ushort4*)&As1[r * 32 + c0] = l0;
            *(ushort4*)&As1[r * 32 + c0 + 4] = l1;
        }
        // stage B: 64 rows x 32 cols
        {
            const int r = tid >> 2;
            const float* src = Bw + (size_t)r * DINNER + kbase + c0;
            float4 v0 = *(const float4*)src;
            float4 v1 = *(const float4*)(src + 4);
            float vv[8] = {v0.x, v0.y, v0.z, v0.w, v1.x, v1.y, v1.z, v1.w};
            ushort4 h0, h1, l0, l1;
            h0.x = f2bf(vv[0]); l0.x = f2bf(vv[0] - bf2f(h0.x));
            h0.y = f2bf(vv[1]); l0.y = f2bf(vv[1] - bf2f(h0.y));
            h0.z = f2bf(vv[2]); l0.z = f2bf(vv[2] - bf2f(h0.z));
            h0.w = f2bf(vv[3]); l0.w = f2bf(vv[3] - bf2f(h0.w));
            h1.x = f2bf(vv[4]); l1.x = f2bf(vv[4] - bf2f(h1.x));
            h1.y = f2bf(vv[5]); l1.y = f2bf(vv[5] - bf2f(h1.y));
            h1.z = f2bf(vv[6]); l1.z = f2bf(vv[6] - bf2f(h1.z));
            h1.w = f2bf(vv[7]); l1.w = f2bf(vv[7] - bf2f(h1.w));
            *(ushort4*)&Bs0[r * 32 + c0] = h0;
            *(ushort4*)&Bs0[r * 32 + c0 + 4] = h1;
            *(ushort4*)&Bs1[r * 32 + c0] = l0;
            *(ushort4*)&Bs1[r * 32 + c0 + 4] = l1;
        }
        __syncthreads();
        bf16x8 ah[4], al[4], bh[2], bl[2];
#pragma unroll
        for (int i = 0; i < 4; i++) {
            ah[i] = *(const bf16x8*)&As0[(wm + i * 16 + l15) * 32 + lk8];
            al[i] = *(const bf16x8*)&As1[(wm + i * 16 + l15) * 32 + lk8];
        }
#pragma unroll
        for (int j = 0; j < 2; j++) {
            bh[j] = *(const bf16x8*)&Bs0[(wn + j * 16 + l15) * 32 + lk8];
            bl[j] = *(const bf16x8*)&Bs1[(wn + j * 16 + l15) * 32 + lk8];
        }
#pragma unroll
        for (int i = 0; i < 4; i++)
#pragma unroll
            for (int j = 0; j < 2; j++) {
                acc[i][j] = __builtin_amdgcn_mfma_f32_16x16x32_bf16(ah[i], bh[j], acc[i][j], 0, 0, 0);
                acc[i][j] = __builtin_amdgcn_mfma_f32_16x16x32_bf16(ah[i], bl[j], acc[i][j], 0, 0, 0);
                acc[i][j] = __builtin_amdgcn_mfma_f32_16x16x32_bf16(al[i], bh[j], acc[i][j], 0, 0, 0);
            }
    }
    float* out = part + (size_t)ks * NTOK * 64;
#pragma unroll
    for (int i = 0; i < 4; i++) {
#pragma unroll
        for (int j = 0; j < 2; j++) {
            const int r0 = row0 + wm + i * 16 + (l >> 4) * 4;
            const int cc = wn + j * 16 + l15;
#pragma unroll
            for (int r = 0; r < 4; r++)
                out[(size_t)(r0 + r) * 64 + cc] = acc[i][j][r];
        }
    }
}

// sum XP_KS partial slices into dbc
__global__ __launch_bounds__(256) void xproj_reduce(const float* __restrict__ part,
                                                    float* __restrict__ dbc) {
    const int i = blockIdx.x * 256 + threadIdx.x; // float4 index, NTOK*64/4 total
    float4 s = ((const float4*)part)[i];
#pragma unroll
    for (int ks = 1; ks < XP_KS; ks++) {
        float4 v = ((const float4*)part)[(size_t)ks * (NTOK * 16) + i];
        s.x += v.x; s.y += v.y; s.z += v.z; s.w += v.w;
    }
    ((float4*)dbc)[i] = s;
}

// ---------------- fp32 GEMM C[M,N] = A[M,K]*B[N,K]^T (dt_proj) ----
template <int EPI>
__global__ __launch_bounds__(256) void gemm_abt(const float* __restrict__ A, int lda,
                                                const float* __restrict__ B, int ldb,
                                                float* __restrict__ C,
                                                const float* __restrict__ bias,
                                                int M, int N, int K) {
    __shared__ float As[16][68];
    __shared__ float Bs[16][68];
    const int tid = threadIdx.x;
    const int row0 = blockIdx.y * 64;
    const int col0 = blockIdx.x * 64;
    const int trow = tid >> 4;
    const int tcol = tid & 15;
    const int lr = tid >> 2;
    const int lk = (tid & 3) * 4;

    float acc[4][4] = {};
    for (int k0 = 0; k0 < K; k0 += 16) {
        float4 av = *(const float4*)&A[(size_t)(row0 + lr) * lda + k0 + lk];
        float4 bv = *(const float4*)&B[(size_t)(col0 + lr) * ldb + k0 + lk];
        __syncthreads();
        As[lk + 0][lr] = av.x; As[lk + 1][lr] = av.y;
        As[lk + 2][lr] = av.z; As[lk + 3][lr] = av.w;
        Bs[lk + 0][lr] = bv.x; Bs[lk + 1][lr] = bv.y;
        Bs[lk + 2][lr] = bv.z; Bs[lk + 3][lr] = bv.w;
        __syncthreads();
#pragma unroll
        for (int k = 0; k < 16; k++) {
            float4 a4 = *(const float4*)&As[k][trow << 2];
            float4 b4 = *(const float4*)&Bs[k][tcol << 2];
            float am[4] = {a4.x, a4.y, a4.z, a4.w};
            float bn[4] = {b4.x, b4.y, b4.z, b4.w};
#pragma unroll
            for (int i = 0; i < 4; i++)
#pragma unroll
                for (int j = 0; j < 4; j++)
                    acc[i][j] = fmaf(am[i], bn[j], acc[i][j]);
        }
    }
#pragma unroll
    for (int i = 0; i < 4; i++) {
        int r = row0 + (trow << 2) + i;
        int cbase = col0 + (tcol << 2);
        float4 o;
        if (EPI == 1) {
            o.x = softplusf_(acc[i][0] + bias[cbase + 0]);
            o.y = softplusf_(acc[i][1] + bias[cbase + 1]);
            o.z = softplusf_(acc[i][2] + bias[cbase + 2]);
            o.w = softplusf_(acc[i][3] + bias[cbase + 3]);
        } else {
            o.x = acc[i][0]; o.y = acc[i][1]; o.z = acc[i][2]; o.w = acc[i][3];
        }
        *(float4*)&C[(size_t)r * N + cbase] = o;
    }
}

// ---------------- depthwise causal conv (D_CONV=4) + SiLU ----------------
__global__ __launch_bounds__(256) void conv_silu_kernel(const float* __restrict__ xin,
                                                        const float* __restrict__ cw,
                                                        const float* __restrict__ cb,
                                                        float* __restrict__ xc) {
    int idx = blockIdx.x * 256 + threadIdx.x; // NTOK*DINNER
    int ch = idx & (DINNER - 1);
    int t = idx >> 10;
    int n = t & (SEQ - 1);
    const float* base = xin + (size_t)t * DINNER + ch;
    const float* wv = cw + ch * 4;
    float acc = cb[ch];
    if (n >= 3) acc = fmaf(wv[0], base[-3 * DINNER], acc);
    if (n >= 2) acc = fmaf(wv[1], base[-2 * DINNER], acc);
    if (n >= 1) acc = fmaf(wv[2], base[-1 * DINNER], acc);
    acc = fmaf(wv[3], base[0], acc);
    xc[idx] = siluf_(acc);
}

// ---------------- selective scan, chunked ----------------
__global__ __launch_bounds__(256) void scan1_kernel(const float* __restrict__ delta,
                                                    const float* __restrict__ xc,
                                                    const float* __restrict__ dbc,
                                                    const float* __restrict__ A_log,
                                                    float* __restrict__ P,
                                                    float* __restrict__ HL) {
    int blk = blockIdx.x; // b*128 + c*4 + dg
    int dg = blk & 3;
    int c = (blk >> 2) & (NCH - 1);
    int b = blk >> 7;
    int d = dg * 256 + threadIdx.x;

    float a[DSTATE], h[DSTATE], p[DSTATE];
#pragma unroll
    for (int s = 0; s < DSTATE; s++) {
        a[s] = -__expf(A_log[d * DSTATE + s]);
        h[s] = 0.f;
        p[s] = 1.f;
    }
    int rowbase = b * SEQ + c * CHUNK;
    for (int i = 0; i < CHUNK; i++) {
        size_t row = rowbase + i;
        float dlt = delta[row * DINNER + d];
        float u = xc[row * DINNER + d];
        float du = dlt * u;
        const float* bs = dbc + row * 64 + DTRANK;
#pragma unroll
        for (int s = 0; s < DSTATE; s++) {
            float ex = __expf(dlt * a[s]);
            h[s] = fmaf(ex, h[s], du * bs[s]);
            p[s] *= ex;
        }
    }
    size_t o = ((size_t)(b * NCH + c) * DINNER + d) * DSTATE;
#pragma unroll
    for (int s = 0; s < DSTATE; s += 4) {
        *(float4*)&P[o + s] = make_float4(p[s], p[s + 1], p[s + 2], p[s + 3]);
        *(float4*)&HL[o + s] = make_float4(h[s], h[s + 1], h[s + 2], h[s + 3]);
    }
}

__global__ __launch_bounds__(256) void scan2_kernel(const float* __restrict__ P,
                                                    float* __restrict__ HL) {
    int idx = blockIdx.x * 256 + threadIdx.x; // BSZ*DINNER*DSTATE = 65536
    int b = idx >> 14;
    int ds = idx & 16383;
    float H = 0.f;
    for (int c = 0; c < NCH; c++) {
        size_t o = ((size_t)(b * NCH + c) << 14) + ds;
        float pv = P[o];
        float hl = HL[o];
        HL[o] = H;
        H = fmaf(pv, H, hl);
    }
}

// pass 3: rescan + fused epilogue; writes y as split bf16 for out_proj MFMA
__global__ __launch_bounds__(256) void scan3_kernel(const float* __restrict__ delta,
                                                    const float* __restrict__ xc,
                                                    const float* __restrict__ zbuf,
                                                    const float* __restrict__ dbc,
                                                    const float* __restrict__ A_log,
                                                    const float* __restrict__ Dp,
                                                    const float* __restrict__ HL,
                                                    ushort* __restrict__ yhi,
                                                    ushort* __restrict__ ylo) {
    int blk = blockIdx.x;
    int dg = blk & 3;
    int c = (blk >> 2) & (NCH - 1);
    int b = blk >> 7;
    int d = dg * 256 + threadIdx.x;

    float a[DSTATE], h[DSTATE];
    size_t o = ((size_t)(b * NCH + c) * DINNER + d) * DSTATE;
#pragma unroll
    for (int s = 0; s < DSTATE; s++) {
        a[s] = -__expf(A_log[d * DSTATE + s]);
        h[s] = HL[o + s];
    }
    float dd = Dp[d];
    int rowbase = b * SEQ + c * CHUNK;
    for (int i = 0; i < CHUNK; i++) {
        size_t row = rowbase + i;
        float dlt = delta[row * DINNER + d];
        float u = xc[row * DINNER + d];
        float z = zbuf[row * DINNER + d];
        float du = dlt * u;
        const float* bs = dbc + row * 64 + DTRANK;
        const float* cs = dbc + row * 64 + DTRANK + DSTATE;
        float y = 0.f;
#pragma unroll
        for (int s = 0; s < DSTATE; s++) {
            float ex = __expf(dlt * a[s]);
            h[s] = fmaf(ex, h[s], du * bs[s]);
            y = fmaf(h[s], cs[s], y);
        }
        y = fmaf(dd, u, y);
        y *= siluf_(z);
        const ushort hh = f2bf(y);
        yhi[row * DINNER + d] = hh;
        ylo[row * DINNER + d] = f2bf(y - bf2f(hh));
    }
}

// ---------------- LayerNorm + mask (reads bf16 hi/lo pair) ----------------
__global__ __launch_bounds__(256) void ln_kernel(const ushort* __restrict__ Xh,
                                                 const ushort* __restrict__ Xl,
                                                 const int* __restrict__ mask,
                                                 const float* __restrict__ nw,
                                                 const float* __restrict__ nb,
                                                 float* __restrict__ out) {
    int wave = threadIdx.x >> 6;
    int lane = threadIdx.x & 63;
    int row = blockIdx.x * 4 + wave;
    int cb = lane * 8;
    const ushort* hr = Xh + (size_t)row * DMODEL + cb;
    const ushort* lr = Xl + (size_t)row * DMODEL + cb;
    ushort4 h0 = *(const ushort4*)&hr[0];
    ushort4 h1 = *(const ushort4*)&hr[4];
    ushort4 l0 = *(const ushort4*)&lr[0];
    ushort4 l1 = *(const ushort4*)&lr[4];
    float xv[8];
    xv[0] = bf2f(h0.x) + bf2f(l0.x);
    xv[1] = bf2f(h0.y) + bf2f(l0.y);
    xv[2] = bf2f(h0.z) + bf2f(l0.z);
    xv[3] = bf2f(h0.w) + bf2f(l0.w);
    xv[4] = bf2f(h1.x) + bf2f(l1.x);
    xv[5] = bf2f(h1.y) + bf2f(l1.y);
    xv[6] = bf2f(h1.z) + bf2f(l1.z);
    xv[7] = bf2f(h1.w) + bf2f(l1.w);
    float sum = 0.f;
#pragma unroll
    for (int j = 0; j < 8; j++) sum += xv[j];
#pragma unroll
    for (int off = 32; off >= 1; off >>= 1) sum += __shfl_xor(sum, off, 64);
    float mu = sum * (1.f / DMODEL);
    float vs = 0.f;
    float dv[8];
#pragma unroll
    for (int j = 0; j < 8; j++) { dv[j] = xv[j] - mu; vs += dv[j] * dv[j]; }
#pragma unroll
    for (int off = 32; off >= 1; off >>= 1) vs += __shfl_xor(vs, off, 64);
    float sc = rsqrtf(vs * (1.f / DMODEL) + LN_EPS);
    float mk = mask[row] ? 1.f : 0.f;
    float4 w0 = *(const float4*)&nw[cb];
    float4 w1 = *(const float4*)&nw[cb + 4];
    float4 b0 = *(const float4*)&nb[cb];
    float4 b1 = *(const float4*)&nb[cb + 4];
    float4 o0, o1;
    o0.x = (dv[0] * sc * w0.x + b0.x) * mk;
    o0.y = (dv[1] * sc * w0.y + b0.y) * mk;
    o0.z = (dv[2] * sc * w0.z + b0.z) * mk;
    o0.w = (dv[3] * sc * w0.w + b0.w) * mk;
    o1.x = (dv[4] * sc * w1.x + b1.x) * mk;
    o1.y = (dv[5] * sc * w1.y + b1.y) * mk;
    o1.z = (dv[6] * sc * w1.z + b1.z) * mk;
    o1.w = (dv[7] * sc * w1.w + b1.w) * mk;
    float* orow = out + (size_t)row * DMODEL + cb;
    *(float4*)&orow[0] = o0;
    *(float4*)&orow[4] = o1;
}

extern "C" void kernel_launch(void* const* d_in, const int* in_sizes, int n_in,
                              void* d_out, int out_size, void* d_ws, size_t ws_size,
                              hipStream_t stream) {
    const float* x = (const float*)d_in[0];
    const int* mask = (const int*)d_in[1];
    const float* ipw = (const float*)d_in[2];
    const float* cw = (const float*)d_in[3];
    const float* cb = (const float*)d_in[4];
    const float* xpw = (const float*)d_in[5];
    const float* dtw = (const float*)d_in[6];
    const float* dtb = (const float*)d_in[7];
    const float* Alog = (const float*)d_in[8];
    const float* Dp = (const float*)d_in[9];
    const float* opw = (const float*)d_in[10];
    const float* nw = (const float*)d_in[11];
    const float* nb = (const float*)d_in[12];

    char* p = (char*)d_ws;
    float* xcpre = (float*)p; p += (size_t)NTOK * DINNER * 4;   // 32MB (aliased by Yhi/Ylo after conv)
    float* zbuf  = (float*)p; p += (size_t)NTOK * DINNER * 4;   // 32MB
    float* xc    = (float*)p; p += (size_t)NTOK * DINNER * 4;   // 32MB
    float* dbc   = (float*)p; p += (size_t)NTOK * 64 * 4;       // 2MB
    float* delta = (float*)p; p += (size_t)NTOK * DINNER * 4;   // 32MB
    float* P     = (float*)p; p += (size_t)BSZ * NCH * DINNER * DSTATE * 4; // 8MB
    float* HL    = (float*)p; p += (size_t)BSZ * NCH * DINNER * DSTATE * 4; // 8MB
    ushort* Xhi  = (ushort*)p; p += (size_t)NTOK * DMODEL * 2;  // 8MB
    ushort* Xlo  = (ushort*)p; p += (size_t)NTOK * DMODEL * 2;  // 8MB
    ushort* Wihi = (ushort*)p; p += (size_t)3 * 2 * DINNER * DMODEL * 2; // 6.3MB
    ushort* Wilo = (ushort*)p; p += (size_t)3 * 2 * DINNER * DMODEL * 2;
    ushort* Wohi = (ushort*)p; p += (size_t)3 * DMODEL * DINNER * 2;     // 3.1MB
    ushort* Wolo = (ushort*)p; p += (size_t)3 * DMODEL * DINNER * 2;
    ushort* Yhi = (ushort*)xcpre;            // alias: xcpre dead after conv
    ushort* Ylo = Yhi + (size_t)NTOK * DINNER;
    float* dbc_part = delta;                 // alias: delta dead until dt_proj

    // weight splits (once per launch)
    split_kernel<<<(3 * 2 * DINNER * DMODEL) / 1024, 256, 0, stream>>>(ipw, Wihi, Wilo);
    split_kernel<<<(3 * DMODEL * DINNER) / 1024, 256, 0, stream>>>(opw, Wohi, Wolo);
    // x0 = mask*x, split
    mask_split_kernel<<<(NTOK * DMODEL) / 1024, 256, 0, stream>>>(x, mask, Xhi, Xlo);

    for (int l = 0; l < 3; l++) {
        const ushort* Wihi_l = Wihi + (size_t)l * 2 * DINNER * DMODEL;
        const ushort* Wilo_l = Wilo + (size_t)l * 2 * DINNER * DMODEL;
        const ushort* Wohi_l = Wohi + (size_t)l * DMODEL * DINNER;
        const ushort* Wolo_l = Wolo + (size_t)l * DMODEL * DINNER;
        const float* cw_l = cw + (size_t)l * DINNER * 4;
        const float* cb_l = cb + (size_t)l * DINNER;
        const float* xpw_l = xpw + (size_t)l * 64 * DINNER;
        const float* dtw_l = dtw + (size_t)l * DINNER * DTRANK;
        const float* dtb_l = dtb + (size_t)l * DINNER;
        const float* Alog_l = Alog + (size_t)l * DINNER * DSTATE;
        const float* Dp_l = Dp + (size_t)l * DINNER;

        // in_proj: both halves in one dispatch (z-dim picks B-panel & dest)
        dim3 gi(DINNER / 128, NTOK / 128, 2); // (8, 64, 2) -> 1024 blocks
        gemm_split3<false><<<gi, 256, 0, stream>>>(
            Xhi, Xlo, Wihi_l, Wilo_l, xcpre, zbuf, (size_t)DINNER * DMODEL,
            nullptr, nullptr, DINNER, DMODEL);
        conv_silu_kernel<<<NTOK * DINNER / 256, 256, 0, stream>>>(xcpre, cw_l, cb_l, xc);
        // x_proj: split-K MFMA with in-kernel fp32->hi/lo staging
        dim3 gx(XP_KS, NTOK / 128); // (8, 64) -> 512 blocks
        xproj_mfma<<<gx, 256, 0, stream>>>(xc, xpw_l, dbc_part);
        xproj_reduce<<<NTOK * 64 / 4 / 256, 256, 0, stream>>>(dbc_part, dbc);
        // dt_proj (fp32) + softplus
        dim3 g3(DINNER / 64, NTOK / 64);
        gemm_abt<1><<<g3, 256, 0, stream>>>(dbc, 64, dtw_l, DTRANK, delta, dtb_l,
                                            NTOK, DINNER, DTRANK);
        scan1_kernel<<<BSZ * NCH * 4, 256, 0, stream>>>(delta, xc, dbc, Alog_l, P, HL);
        scan2_kernel<<<BSZ * DINNER * DSTATE / 256, 256, 0, stream>>>(P, HL);
        scan3_kernel<<<BSZ * NCH * 4, 256, 0, stream>>>(delta, xc, zbuf, dbc, Alog_l, Dp_l,
                                                        HL, Yhi, Ylo);
        // out_proj: fused MFMA, split output straight into next layer's X pair
        dim3 go(DMODEL / 128, NTOK / 128, 1); // (4, 64) -> 256 blocks
        gemm_split3<true><<<go, 256, 0, stream>>>(
            Yhi, Ylo, Wohi_l, Wolo_l, nullptr, nullptr, 0, Xhi, Xlo, DMODEL, DINNER);
    }
    ln_kernel<<<NTOK / 4, 256, 0, stream>>>(Xhi, Xlo, mask, nw, nb, (float*)d_out);
}